// Round 16
// baseline (370.384 us; speedup 1.0000x reference)
//
#include <hip/hip_runtime.h>
#include <stdint.h>

// Segment layout (elements in each battle row of 10451 floats):
//  player 9 @0 | status 86 @9 | pinfo 8 @95 | 13 x card(740) @103 | potions 43 @9723
//  | relics 180 @9766 | 5 x monster(101) @9946
// Output row (542 floats): player4 @0 | status16 @4 | pinfo2 @20 | cards 13*32 @22
//  | potions8 @438 | relics16 @446 | monsters 5*16 @462
//
// BARRIER-FREE card path (R15 + fix): each WAVE owns battle rows
// independently, staging into a wave-PRIVATE LDS region. R15 NaN root cause:
// hipcc does NOT order global_load_lds DMA writes vs later ds_reads without
// a barrier -- the fix is an explicit PER-WAVE s_waitcnt vmcnt(0) between
// stage and compute (not a barrier; waits only on this wave's own DMA).
// 8 independent wave-actors/CU, s_sleep phase stagger, stride-388 slices
// (conflict-free b128). Small segments: R7 windowed-LDS blocks at grid end.

typedef __attribute__((ext_vector_type(8))) short short8;
typedef __attribute__((ext_vector_type(4))) float f32x4;

__device__ inline unsigned short f2bf(float f) {
  union { float f; uint32_t u; } v; v.f = f;
  uint32_t r = v.u + 0x7FFFu + ((v.u >> 16) & 1u);   // round-to-nearest-even
  return (unsigned short)(r >> 16);
}

// packed bf16 pair via the HW converter (RNE), 1 VALU op for 2 elements
__device__ inline uint32_t cvt2(float lo, float hi) {
  uint32_t r;
  asm("v_cvt_pk_bf16_f32 %0, %1, %2" : "=v"(r) : "v"(lo), "v"(hi));
  return r;
}

union bfrag { short8 s; uint32_t u[4]; };

__device__ inline short8 mk_frag(f32x4 lo, f32x4 hi) {
  bfrag f;
  f.u[0] = cvt2(lo[0], lo[1]);
  f.u[1] = cvt2(lo[2], lo[3]);
  f.u[2] = cvt2(hi[0], hi[1]);
  f.u[3] = cvt2(hi[2], hi[3]);
  return f.s;
}

__device__ inline void gload_dw(const float* g, float* lds) {
  __builtin_amdgcn_global_load_lds(
      (const __attribute__((address_space(1))) void*)g,
      (__attribute__((address_space(3))) void*)lds, 4, 0, 0);
}

// Card W -> fragment-interleaved bf16: dword idx = cs*512 + wn*256 + kg*64 + rl*4 + d
// where cs (0..23) covers k = cs*32 + kg*8 + d*2; n = wn*16 + rl. Zero-padded
// beyond k=740. 12288 dwords = 48 KB.
__global__ __launch_bounds__(256) void pack_w(const float* __restrict__ Wc,
                                              uint32_t* __restrict__ wout) {
  int el = blockIdx.x * 256 + threadIdx.x;
  if (el >= 12288) return;
  int d  = el & 3;
  int rl = (el >> 2) & 15;
  int kg = (el >> 6) & 3;
  int wn = (el >> 8) & 1;
  int cs = el >> 9;
  int n  = wn * 16 + rl;
  int k  = cs * 32 + kg * 8 + d * 2;
  float v0 = (k     < 740) ? Wc[n * 740 + k]     : 0.0f;
  float v1 = (k + 1 < 740) ? Wc[n * 740 + k + 1] : 0.0f;
  wout[el] = (uint32_t)f2bf(v0) | ((uint32_t)f2bf(v1) << 16);
}

__global__ __launch_bounds__(256, 2) void seg_gemm(
    const float* __restrict__ battle,
    const float* __restrict__ Wplayer, const float* __restrict__ Wstatus,
    const float* __restrict__ Wpinfo,  const float* __restrict__ Wpotions,
    const float* __restrict__ Wrelics, const float* __restrict__ Wmonster,
    const uint32_t* __restrict__ wpack2,
    float* __restrict__ out, const float* __restrict__ zpage)
{
  // card: 4 waves x 5120-float private regions (81920 B); small path uses 5120.
  __shared__ float shm[20480];
  const int bid  = blockIdx.x;
  const int t    = threadIdx.x;
  const int lane = t & 63;
  const int wv   = t >> 6;
  const int rl   = lane & 15;
  const int kg   = lane >> 4;

  if (bid < 4096) {
    // =============== card path: wave-autonomous, NO barriers ===============
    float* wbuf = &shm[wv * 5120];
    // phase stagger: ~gw*384 cycles, decorrelates the 8 waves/CU
    const int gw = ((bid << 2) | wv) & 7;
    for (int i = 0; i < gw; ++i) __builtin_amdgcn_s_sleep(6);

    #pragma unroll 1
    for (int rr = 0; rr < 2; ++rr) {
      const uint32_t brow = (uint32_t)(bid * 8 + wv * 2 + rr);
      const uint32_t row  = brow * 10451u + 103u;

      f32x4 acc0 = {0.f, 0.f, 0.f, 0.f};
      f32x4 acc1 = {0.f, 0.f, 0.f, 0.f};

      #pragma unroll 1
      for (int h = 0; h < 2; ++h) {
        // ---- stage k-half h: 13 slices x 384 floats, slice stride 388 ----
        #pragma unroll
        for (int s = 0; s < 13; ++s)
          #pragma unroll
          for (int j = 0; j < 6; ++j)
            gload_dw(battle + row + (uint32_t)(s * 740 + h * 384 + j * 64 + lane),
                     &wbuf[s * 388 + j * 64 + lane]);

        // PER-WAVE drain of this wave's own DMA (not a barrier). hipcc does
        // not order global_load_lds writes vs ds_reads on its own (R15 NaN).
        asm volatile("s_waitcnt vmcnt(0)" ::: "memory");

        // ---- compute 12 chunks from the wave-private buffer ----
        const uint32_t abase = (rl < 13) ? (uint32_t)(rl * 388) : 0u;
        #pragma unroll
        for (int c = 0; c < 12; ++c) {
          const int cs = h * 12 + c;
          const float* ap = wbuf + abase + (uint32_t)(c * 32 + kg * 8);
          f32x4 lo = *(const f32x4*)ap;
          f32x4 hi = *(const f32x4*)(ap + 4);
          short8 aa = mk_frag(lo, hi);
          short8 w0 = *(const short8*)(wpack2 + (uint32_t)(cs * 512 + kg * 64 + rl * 4));
          short8 w1 = *(const short8*)(wpack2 + (uint32_t)(cs * 512 + 256 + kg * 64 + rl * 4));
          acc0 = __builtin_amdgcn_mfma_f32_16x16x32_bf16(aa, w0, acc0, 0, 0, 0);
          acc1 = __builtin_amdgcn_mfma_f32_16x16x32_bf16(aa, w1, acc1, 0, 0, 0);
        }
        // h=0 ds_reads are all consumed (compiler lgkmcnt before MFMA use)
        // before h=1's DMA can overwrite wbuf -- no extra wait needed.
      }

      // ---- epilogue: C/D row = kg*4+q (sub), col = rl; both n-halves ----
      const uint32_t ob = brow * 542u + 22u;
      #pragma unroll
      for (int q = 0; q < 4; ++q) {
        const int sub = kg * 4 + q;
        if (sub < 13) {
          out[ob + (uint32_t)(sub * 32 + rl)]      = acc0[q];
          out[ob + (uint32_t)(sub * 32 + 16 + rl)] = acc1[q];
        }
      }
    }
    return;
  }

  // ======================= small-segment path (R7 structure) =======================
  const int sb = bid - 4096;                     // 0..2559
  int bloc, nsub, K, NOUT, soff, ooff;
  const float* wp;
  if (sb < 1280)      { bloc = sb;        nsub = 5; K = 101; NOUT = 16; soff = 9946; ooff = 462; wp = Wmonster; }
  else if (sb < 1536) { bloc = sb - 1280; nsub = 1; K = 180; NOUT = 16; soff = 9766; ooff = 446; wp = Wrelics; }
  else if (sb < 1792) { bloc = sb - 1536; nsub = 1; K = 86;  NOUT = 16; soff = 9;    ooff = 4;   wp = Wstatus; }
  else if (sb < 2048) { bloc = sb - 1792; nsub = 1; K = 43;  NOUT = 8;  soff = 9723; ooff = 438; wp = Wpotions; }
  else if (sb < 2304) { bloc = sb - 2048; nsub = 1; K = 9;   NOUT = 4;  soff = 0;    ooff = 0;   wp = Wplayer; }
  else                { bloc = sb - 2304; nsub = 1; K = 8;   NOUT = 2;  soff = 95;   ooff = 20;  wp = Wpinfo; }

  float* lds_a = shm;            // [128][32] fp32, 16B-granule XOR-swizzled
  float* lds_w = shm + 4096;     // [32][32]

  const int mb = bloc * 128;
  const int r0 = t >> 5;

  uint32_t rb[16];
  #pragma unroll
  for (int i = 0; i < 16; ++i) {
    uint32_t m   = (uint32_t)(mb + r0 + 8 * i);
    uint32_t b   = m / (uint32_t)nsub;
    uint32_t sub = m - b * (uint32_t)nsub;
    rb[i] = b * 10451u + (uint32_t)soff + sub * (uint32_t)K;
  }

  const int klin = t & 31;
  const int lk   = (((klin >> 2) ^ r0) << 2) | (klin & 3);

  f32x4 acc[2] = {};
  const int nch = (K + 31) >> 5;

  for (int ch = 0; ch < nch; ++ch) {
    const int kk = (ch << 5) + lk;
    #pragma unroll
    for (int i = 0; i < 16; ++i) {
      const float* sp = (kk < K) ? (battle + rb[i] + kk) : zpage;
      gload_dw(sp, &lds_a[i * 256 + t]);
    }
    #pragma unroll
    for (int i = 0; i < 4; ++i) {
      const int col = r0 + 8 * i;
      const float* sp = (col < NOUT && kk < K) ? (wp + col * K + kk) : zpage;
      gload_dw(sp, &lds_w[i * 256 + t]);
    }
    __syncthreads();

    short8 af[2], bfr;
    #pragma unroll
    for (int mf = 0; mf < 2; ++mf) {
      const int rr  = wv * 32 + mf * 16 + rl;
      const int g0i = (2 * kg) ^ (rr & 7);
      const int g1i = (2 * kg + 1) ^ (rr & 7);
      f32x4 lo = *(const f32x4*)&lds_a[rr * 32 + g0i * 4];
      f32x4 hi = *(const f32x4*)&lds_a[rr * 32 + g1i * 4];
      af[mf] = mk_frag(lo, hi);
    }
    {
      const int c   = rl;            // NOUT <= 16 for all small segments
      const int g0i = (2 * kg) ^ (c & 7);
      const int g1i = (2 * kg + 1) ^ (c & 7);
      f32x4 lo = *(const f32x4*)&lds_w[c * 32 + g0i * 4];
      f32x4 hi = *(const f32x4*)&lds_w[c * 32 + g1i * 4];
      bfr = mk_frag(lo, hi);
    }
    #pragma unroll
    for (int mf = 0; mf < 2; ++mf)
      acc[mf] = __builtin_amdgcn_mfma_f32_16x16x32_bf16(af[mf], bfr, acc[mf], 0, 0, 0);

    __syncthreads();
  }

  #pragma unroll
  for (int mf = 0; mf < 2; ++mf) {
    #pragma unroll
    for (int q = 0; q < 4; ++q) {
      uint32_t m   = (uint32_t)(mb + wv * 32 + mf * 16 + kg * 4 + q);
      uint32_t b   = m / (uint32_t)nsub;
      uint32_t sub = m - b * (uint32_t)nsub;
      uint32_t ob  = b * 542u + (uint32_t)ooff + sub * (uint32_t)NOUT;
      const int col = rl;
      if (col < NOUT) out[ob + col] = acc[mf][q];
    }
  }
}

extern "C" void kernel_launch(void* const* d_in, const int* in_sizes, int n_in,
                              void* d_out, int out_size, void* d_ws, size_t ws_size,
                              hipStream_t stream) {
  const float* battle   = (const float*)d_in[0];
  const float* Wplayer  = (const float*)d_in[1];
  const float* Wstatus  = (const float*)d_in[2];
  const float* Wpinfo   = (const float*)d_in[3];
  const float* Wcard    = (const float*)d_in[4];
  const float* Wpotions = (const float*)d_in[5];
  const float* Wrelics  = (const float*)d_in[6];
  const float* Wmonster = (const float*)d_in[7];
  float* out = (float*)d_out;

  // ws layout: [0,256) zero page | [256, 256+49152) frag-interleaved card W
  const float* zpage = (const float*)d_ws;
  uint32_t* wpack2 = (uint32_t*)((char*)d_ws + 256);

  hipMemsetAsync(d_ws, 0, 256, stream);
  hipLaunchKernelGGL(pack_w, dim3(48), dim3(256), 0, stream, Wcard, wpack2);
  hipLaunchKernelGGL(seg_gemm, dim3(6656), dim3(256), 0, stream,
                     battle, Wplayer, Wstatus, Wpinfo, Wpotions, Wrelics,
                     Wmonster, (const uint32_t*)wpack2, out, zpage);
}

// Round 17
// 296.994 us; speedup vs baseline: 1.2471x; 1.2471x over previous
//
#include <hip/hip_runtime.h>
#include <stdint.h>

// Segment layout (elements in each battle row of 10451 floats):
//  player 9 @0 | status 86 @9 | pinfo 8 @95 | 13 x card(740) @103 | potions 43 @9723
//  | relics 180 @9766 | 5 x monster(101) @9946
// Output row (542 floats): player4 @0 | status16 @4 | pinfo2 @20 | cards 13*32 @22
//  | potions8 @438 | relics16 @446 | monsters 5*16 @462
//
// R14 unified one-row blocks (302us) + COALESCED ROW WRITES: previously each
// accumulator stored 16-float (64B) segments scattered over the 2168B output
// row (half-L2-line partial writes -> RMW amplification). Now the whole
// 542-float row is gathered in LDS (orow) and stored as 3 contiguous
// coalesced bursts. Card path / smalls-as-MFMA-chunks identical to R14.

typedef __attribute__((ext_vector_type(8))) short short8;
typedef __attribute__((ext_vector_type(4))) float f32x4;

__device__ inline unsigned short f2bf(float f) {
  union { float f; uint32_t u; } v; v.f = f;
  uint32_t r = v.u + 0x7FFFu + ((v.u >> 16) & 1u);   // round-to-nearest-even
  return (unsigned short)(r >> 16);
}

// packed bf16 pair via the HW converter (RNE), 1 VALU op for 2 elements
__device__ inline uint32_t cvt2(float lo, float hi) {
  uint32_t r;
  asm("v_cvt_pk_bf16_f32 %0, %1, %2" : "=v"(r) : "v"(lo), "v"(hi));
  return r;
}

union bfrag { short8 s; uint32_t u[4]; };

__device__ inline short8 mk_frag(f32x4 lo, f32x4 hi) {
  bfrag f;
  f.u[0] = cvt2(lo[0], lo[1]);
  f.u[1] = cvt2(lo[2], lo[3]);
  f.u[2] = cvt2(hi[0], hi[1]);
  f.u[3] = cvt2(hi[2], hi[3]);
  return f.s;
}

__device__ inline void gload_dw(const float* g, float* lds) {
  __builtin_amdgcn_global_load_lds(
      (const __attribute__((address_space(1))) void*)g,
      (__attribute__((address_space(3))) void*)lds, 4, 0, 0);
}

// W -> fragment-interleaved bf16. 41 chunks x 512 dwords:
//  chunk 0..23 card | 24..26 status | 27..28 potions | 29 player | 30 pinfo
//  | 31..34 monster | 35..40 relics.
// dword idx = chunk*512 + wn*256 + kg*64 + rl*4 + d holds W[n][k],W[n][k+1]
// with n = wn*16+rl, k = (chunk-cbase)*32 + kg*8 + d*2; zero outside NOUT/K.
__global__ __launch_bounds__(256) void pack_w(
    const float* __restrict__ Wp, const float* __restrict__ Ws,
    const float* __restrict__ Wpi, const float* __restrict__ Wc,
    const float* __restrict__ Wpo, const float* __restrict__ Wr,
    const float* __restrict__ Wm, uint32_t* __restrict__ wout) {
  int el = blockIdx.x * 256 + threadIdx.x;
  if (el >= 20992) return;
  int d  = el & 3;
  int rl = (el >> 2) & 15;
  int kg = (el >> 6) & 3;
  int wn = (el >> 8) & 1;
  int chunk = el >> 9;
  const float* w; int K, NOUT, cbase;
  if (chunk < 24)      { w = Wc;  K = 740; NOUT = 32; cbase = 0; }
  else if (chunk < 27) { w = Ws;  K = 86;  NOUT = 16; cbase = 24; }
  else if (chunk < 29) { w = Wpo; K = 43;  NOUT = 8;  cbase = 27; }
  else if (chunk < 30) { w = Wp;  K = 9;   NOUT = 4;  cbase = 29; }
  else if (chunk < 31) { w = Wpi; K = 8;   NOUT = 2;  cbase = 30; }
  else if (chunk < 35) { w = Wm;  K = 101; NOUT = 16; cbase = 31; }
  else                 { w = Wr;  K = 180; NOUT = 16; cbase = 35; }
  int n = wn * 16 + rl;
  int k = (chunk - cbase) * 32 + kg * 8 + d * 2;
  float v0 = (n < NOUT && k     < K) ? w[n * K + k]     : 0.0f;
  float v1 = (n < NOUT && k + 1 < K) ? w[n * K + k + 1] : 0.0f;
  wout[el] = (uint32_t)f2bf(v0) | ((uint32_t)f2bf(v1) << 16);
}

__global__ __launch_bounds__(256, 3) void seg_gemm(
    const float* __restrict__ battle,
    const uint32_t* __restrict__ wpack2,
    float* __restrict__ out)
{
  // LDS: card[0..9728) | smalls[9728..10608) | wred[10608..11120) | orow[11120..11664)
  __shared__ float shm[11664];
  const int b    = blockIdx.x;          // battle row
  const int t    = threadIdx.x;
  const int lane = t & 63;
  const int wv   = t >> 6;
  const int rl   = lane & 15;
  const int kg   = lane >> 4;
  const int wn   = wv & 1;              // card n-half
  const int wk   = wv >> 1;             // card K-half

  const uint32_t row = (uint32_t)b * 10451u;

  // ---- stage card region [103, 9831) -> shm[0..9728) ----
  #pragma unroll
  for (int r = 0; r < 38; ++r)
    gload_dw(battle + row + 103u + (uint32_t)(r * 256 + t), &shm[r * 256 + t]);

  // ---- stage smalls -> shm[9728..10608): per-lane source map, linear dest --
  // layout: player@0(9) status@12(86) pinfo@100(8) potions@112(43)
  // relics@156(180) monster@336(5 x stride 104)
  #pragma unroll
  for (int r = 0; r < 4; ++r) {
    const int s = r * 256 + t;
    if (s < 880) {
      int src;
      if (s < 12)        src = s;                 // player (+gap: garbage x0)
      else if (s < 100)  src = 9 + (s - 12);      // status (+tail x0)
      else if (s < 112)  src = 95 + (s - 100);    // pinfo
      else if (s < 156)  src = 9723 + (s - 112);  // potions
      else if (s < 336)  src = 9766 + (s - 156);  // relics
      else if (s < 856) {                         // monster, rows padded to 104
        int sub = (s - 336) / 104;
        int kk  = (s - 336) - sub * 104;
        src = 9946 + sub * 101 + ((kk > 100) ? 100 : kk);
      } else src = 0;                             // pad (finite x0)
      gload_dw(battle + row + (uint32_t)src, &shm[9728 + s]);
    }
  }
  __syncthreads();   // drains vmcnt(0); LDS read-only afterwards

  // ======================= card compute (R8 structure) =======================
  const uint32_t abase = (rl < 13) ? (uint32_t)(rl * 740) : 0u;
  float* wred = &shm[10608];
  float* orow = &shm[11120];

  f32x4 acc = {0.f, 0.f, 0.f, 0.f};
  #pragma unroll
  for (int si = 0; si < 12; ++si) {
    const int cs = wk * 12 + si;        // k = cs*32 + kg*8 (+0..7)
    const float* ap = shm + abase + (uint32_t)(cs * 32 + kg * 8);
    f32x4 lo = *(const f32x4*)ap;
    f32x4 hi = *(const f32x4*)(ap + 4);
    short8 aa = mk_frag(lo, hi);
    short8 wf = *(const short8*)(wpack2 + (uint32_t)(cs * 512 + wn * 256 + kg * 64 + rl * 4));
    acc = __builtin_amdgcn_mfma_f32_16x16x32_bf16(aa, wf, acc, 0, 0, 0);
  }

  if (wk == 1) {
    #pragma unroll
    for (int q = 0; q < 4; ++q)
      wred[wn * 256 + (kg * 4 + q) * 16 + rl] = acc[q];
  }
  __syncthreads();

  if (wk == 0) {
    #pragma unroll
    for (int q = 0; q < 4; ++q) {
      const int sub = kg * 4 + q;       // C/D: row = kg*4+q, col = rl
      float v = acc[q] + wred[wn * 256 + (kg * 4 + q) * 16 + rl];
      if (sub < 13)
        orow[22 + sub * 32 + wn * 16 + rl] = v;
    }
  }

  // ======================= small segments (waves 0-2) -> orow =======================
  #define DO_SEG(CBASE, NCH, SBOFF, STRIDE, M, NOUTS, OOFF) do {               \
    f32x4 sacc = {0.f, 0.f, 0.f, 0.f};                                         \
    _Pragma("unroll")                                                          \
    for (int c = 0; c < (NCH); ++c) {                                          \
      const uint32_t ab = 9728u + (SBOFF) +                                    \
                          ((rl < (M)) ? (uint32_t)(rl * (STRIDE)) : 0u);       \
      const float* ap = shm + ab + (uint32_t)(c * 32 + kg * 8);                \
      f32x4 lo = *(const f32x4*)ap;                                            \
      f32x4 hi = *(const f32x4*)(ap + 4);                                      \
      short8 aa = mk_frag(lo, hi);                                             \
      short8 wf = *(const short8*)(wpack2 +                                    \
                    (uint32_t)(((CBASE) + c) * 512 + kg * 64 + rl * 4));       \
      sacc = __builtin_amdgcn_mfma_f32_16x16x32_bf16(aa, wf, sacc, 0, 0, 0);   \
    }                                                                          \
    _Pragma("unroll")                                                          \
    for (int q = 0; q < 4; ++q) {                                              \
      const int rowq = kg * 4 + q;                                             \
      if (rowq < (M) && rl < (NOUTS))                                          \
        orow[(OOFF) + rowq * (NOUTS) + rl] = sacc[q];                          \
    }                                                                          \
  } while (0)

  if (wv == 0) {
    DO_SEG(24, 3, 12u,  0, 1, 16, 4);     // status
    DO_SEG(27, 2, 112u, 0, 1, 8,  438);   // potions
    DO_SEG(29, 1, 0u,   0, 1, 4,  0);     // player
    DO_SEG(30, 1, 100u, 0, 1, 2,  20);    // pinfo
  } else if (wv == 1) {
    DO_SEG(31, 4, 336u, 104, 5, 16, 462); // monster
  } else if (wv == 2) {
    DO_SEG(35, 6, 156u, 0, 1, 16, 446);   // relics
  }
  #undef DO_SEG

  // ======================= coalesced row store =======================
  __syncthreads();
  const uint32_t ob0 = (uint32_t)b * 542u;
  #pragma unroll
  for (int i = t; i < 542; i += 256)
    out[ob0 + (uint32_t)i] = orow[i];
}

extern "C" void kernel_launch(void* const* d_in, const int* in_sizes, int n_in,
                              void* d_out, int out_size, void* d_ws, size_t ws_size,
                              hipStream_t stream) {
  const float* battle   = (const float*)d_in[0];
  const float* Wplayer  = (const float*)d_in[1];
  const float* Wstatus  = (const float*)d_in[2];
  const float* Wpinfo   = (const float*)d_in[3];
  const float* Wcard    = (const float*)d_in[4];
  const float* Wpotions = (const float*)d_in[5];
  const float* Wrelics  = (const float*)d_in[6];
  const float* Wmonster = (const float*)d_in[7];
  float* out = (float*)d_out;

  uint32_t* wpack2 = (uint32_t*)d_ws;    // 41*512 dwords = 84 KB packed W

  hipLaunchKernelGGL(pack_w, dim3(82), dim3(256), 0, stream,
                     Wplayer, Wstatus, Wpinfo, Wcard, Wpotions, Wrelics,
                     Wmonster, wpack2);
  hipLaunchKernelGGL(seg_gemm, dim3(32768), dim3(256), 0, stream,
                     battle, (const uint32_t*)wpack2, out);
}